// Round 1
// baseline (2262.584 us; speedup 1.0000x reference)
//
#include <hip/hip_runtime.h>
#include <math.h>

typedef unsigned int u32;
typedef unsigned long long u64;

#define NIMG 8
#define CIN 512
#define COUT 512
#define HF 64
#define WF 64
#define NPOS 4096
#define NANCH 36864
#define NPRE 2000
#define NPOST 300
#define SUPW 32

#define OUT_LOCS   0
#define OUT_SCORES 1179648
#define OUT_ROIS   1769472
#define OUT_ROIIDX 1779072
#define OUT_ANCH   1781472

// ---------- helpers ----------
__device__ __forceinline__ u32 fkey(float f) {
  u32 s = __float_as_uint(f);
  return (s & 0x80000000u) ? ~s : (s | 0x80000000u);   // ascending uint == ascending float
}
__device__ __forceinline__ float unkey(u32 u) {
  u32 s = (u & 0x80000000u) ? (u ^ 0x80000000u) : ~u;
  return __uint_as_float(s);
}
__device__ __forceinline__ void anchor_at(int hq, int wq, int a,
                                          float& a0, float& a1, float& a2, float& a3) {
  const float ratios[3] = {0.5f, 1.0f, 2.0f};
  const float scales[3] = {8.0f, 16.0f, 32.0f};
  float r = ratios[a / 3];
  float s = scales[a % 3];
  float hh = __fmul_rn(__fmul_rn(16.0f, s), sqrtf(r));
  float ww = __fmul_rn(__fmul_rn(16.0f, s), sqrtf(1.0f / r));
  float ab0 = __fsub_rn(8.0f, __fmul_rn(0.5f, hh));
  float ab1 = __fsub_rn(8.0f, __fmul_rn(0.5f, ww));
  float ab2 = __fadd_rn(8.0f, __fmul_rn(0.5f, hh));
  float ab3 = __fadd_rn(8.0f, __fmul_rn(0.5f, ww));
  float y = (float)(hq * 16);
  float x = (float)(wq * 16);
  a0 = __fadd_rn(y, ab0);
  a1 = __fadd_rn(x, ab1);
  a2 = __fadd_rn(y, ab2);
  a3 = __fadd_rn(x, ab3);
}
__device__ __forceinline__ u64 shfl_u64(u64 v, int src) {
  u32 lo = (u32)v, hi = (u32)(v >> 32);
  lo = __shfl(lo, src, 64);
  hi = __shfl(hi, src, 64);
  return ((u64)hi << 32) | (u64)lo;
}

// ---------- weight transposes + anchors + roi_indices ----------
__global__ __launch_bounds__(256) void k_transpose_w(const float* __restrict__ w,
                                                     float* __restrict__ wt) {
  int o = blockIdx.x * 256 + threadIdx.x;
  if (o >= COUT * CIN * 9) return;
  int co = o & 511;
  int r = o >> 9;            // ci*9 + tap
  int tap = r % 9;
  int ci = r / 9;
  wt[o] = w[((size_t)co * CIN + ci) * 9 + tap];
}

__global__ __launch_bounds__(256) void k_prep_small(const float* __restrict__ sw,
                                                    const float* __restrict__ lw,
                                                    float* __restrict__ wt54,
                                                    float* __restrict__ out) {
  int i = blockIdx.x * 256 + threadIdx.x;
  if (i < 512 * 56) {                       // wt54[c][o], o-padded to 56
    int c = i / 56, o = i % 56;
    float v = 0.0f;
    if (o < 18) v = sw[o * 512 + c];
    else if (o < 54) v = lw[(o - 18) * 512 + c];
    wt54[i] = v;
  }
  if (i < NANCH) {                          // anchors output
    int pos = i / 9, a = i % 9;
    float a0, a1, a2, a3;
    anchor_at(pos >> 6, pos & 63, a, a0, a1, a2, a3);
    float* dst = out + OUT_ANCH + (size_t)i * 4;
    dst[0] = a0; dst[1] = a1; dst[2] = a2; dst[3] = a3;
  }
  if (i < NIMG * NPOST) out[OUT_ROIIDX + i] = (float)(i / NPOST);
}

// ---------- conv3x3 512->512 + bias + relu (fp32, LDS-tiled) ----------
#define CC 8
__global__ __launch_bounds__(256) void k_conv3x3(const float* __restrict__ x,
                                                 const float* __restrict__ wt,
                                                 const float* __restrict__ bias,
                                                 float* __restrict__ hidden) {
  __shared__ float in_lds[4][CC][68];       // 68: keep 16B row alignment
  __shared__ float w_lds[CC][9][64];
  const int tid = threadIdx.x;
  const int h0 = blockIdx.x * 2;
  const int n = blockIdx.y;
  const int co_t = blockIdx.z * 64;
  const int wq = tid & 15, cq = tid >> 4;
  const int w0 = wq * 4;
  const float* xn = x + (size_t)n * CIN * NPOS;
  float acc[2][4][4] = {};
  for (int ci0 = 0; ci0 < CIN; ci0 += CC) {
    for (int idx = tid; idx < 4 * CC * 66; idx += 256) {
      int wp = idx % 66;
      int r = idx / 66;
      int cc = r % CC, rr = r / CC;
      int hh = h0 - 1 + rr, ww = wp - 1;
      float v = 0.0f;
      if (hh >= 0 && hh < HF && ww >= 0 && ww < WF)
        v = xn[(size_t)(ci0 + cc) * NPOS + hh * WF + ww];
      in_lds[rr][cc][wp] = v;
    }
    for (int idx = tid; idx < CC * 9 * 64; idx += 256) {
      int co = idx & 63;
      int r = idx >> 6;
      int tap = r % 9, cc = r / 9;
      w_lds[cc][tap][co] = wt[((size_t)(ci0 + cc) * 9 + tap) * COUT + co_t + co];
    }
    __syncthreads();
    for (int cc = 0; cc < CC; ++cc) {
      float a[4][6];
      #pragma unroll
      for (int r = 0; r < 4; ++r)
        #pragma unroll
        for (int k = 0; k < 6; ++k)
          a[r][k] = in_lds[r][cc][w0 + k];
      #pragma unroll
      for (int kh = 0; kh < 3; ++kh) {
        #pragma unroll
        for (int kw = 0; kw < 3; ++kw) {
          const float4 b4 = *(const float4*)&w_lds[cc][kh * 3 + kw][cq * 4];
          #pragma unroll
          for (int r = 0; r < 2; ++r) {
            #pragma unroll
            for (int w = 0; w < 4; ++w) {
              float av = a[r + kh][w + kw];
              acc[r][w][0] = fmaf(av, b4.x, acc[r][w][0]);
              acc[r][w][1] = fmaf(av, b4.y, acc[r][w][1]);
              acc[r][w][2] = fmaf(av, b4.z, acc[r][w][2]);
              acc[r][w][3] = fmaf(av, b4.w, acc[r][w][3]);
            }
          }
        }
      }
    }
    __syncthreads();
  }
  #pragma unroll
  for (int c = 0; c < 4; ++c) {
    float b = bias[co_t + cq * 4 + c];
    #pragma unroll
    for (int r = 0; r < 2; ++r) {
      float4 v;
      v.x = fmaxf(acc[r][0][c] + b, 0.0f);
      v.y = fmaxf(acc[r][1][c] + b, 0.0f);
      v.z = fmaxf(acc[r][2][c] + b, 0.0f);
      v.w = fmaxf(acc[r][3][c] + b, 0.0f);
      *(float4*)&hidden[(((size_t)n * COUT + co_t + cq * 4 + c) * HF + h0 + r) * WF + w0] = v;
    }
  }
}

// ---------- heads: 1x1 convs + softmax-fg + decode + sort keys ----------
__global__ __launch_bounds__(256) void k_heads(const float* __restrict__ hidden,
                                               const float* __restrict__ wt54,
                                               const float* __restrict__ sb,
                                               const float* __restrict__ lb,
                                               const int* __restrict__ ihp,
                                               const int* __restrict__ iwp,
                                               float* __restrict__ out,
                                               float4* __restrict__ boxes_all,
                                               u64* __restrict__ k64) {
  const int n = blockIdx.y;
  const int hw = blockIdx.x * 256 + threadIdx.x;
  const float* hid = hidden + (size_t)n * CIN * NPOS + hw;
  float acc[54];
  #pragma unroll
  for (int o = 0; o < 54; ++o) acc[o] = 0.0f;
  #pragma unroll 4
  for (int c = 0; c < CIN; ++c) {
    float hv = hid[(size_t)c * NPOS];
    const float* wrow = wt54 + c * 56;      // block-uniform -> scalar loads
    #pragma unroll
    for (int o = 0; o < 54; ++o) acc[o] = fmaf(hv, wrow[o], acc[o]);
  }
  float sc18[18];
  #pragma unroll
  for (int o = 0; o < 18; ++o) sc18[o] = __fadd_rn(acc[o], sb[o]);
  float lc36[36];
  #pragma unroll
  for (int o = 0; o < 36; ++o) lc36[o] = __fadd_rn(acc[18 + o], lb[o]);
  {
    float* dst = out + OUT_SCORES + ((size_t)n * NPOS + hw) * 18;
    #pragma unroll
    for (int q = 0; q < 9; ++q) *(float2*)&dst[q * 2] = make_float2(sc18[2 * q], sc18[2 * q + 1]);
  }
  {
    float* dst = out + OUT_LOCS + ((size_t)n * NPOS + hw) * 36;
    #pragma unroll
    for (int q = 0; q < 9; ++q)
      *(float4*)&dst[q * 4] = make_float4(lc36[4 * q], lc36[4 * q + 1], lc36[4 * q + 2], lc36[4 * q + 3]);
  }
  const float fh = (float)ihp[0];
  const float fw = (float)iwp[0];
  const int hq = hw >> 6, wq2 = hw & 63;
  #pragma unroll
  for (int a = 0; a < 9; ++a) {
    float a0, a1, a2, a3;
    anchor_at(hq, wq2, a, a0, a1, a2, a3);
    float ah = __fsub_rn(a2, a0), aw = __fsub_rn(a3, a1);
    float acy = __fadd_rn(a0, __fmul_rn(0.5f, ah));
    float acx = __fadd_rn(a1, __fmul_rn(0.5f, aw));
    float dy = lc36[4 * a], dx = lc36[4 * a + 1], dh = lc36[4 * a + 2], dw = lc36[4 * a + 3];
    float cy = __fadd_rn(__fmul_rn(dy, ah), acy);
    float cx = __fadd_rn(__fmul_rn(dx, aw), acx);
    float hh = __fmul_rn(expf(dh), ah);
    float ww = __fmul_rn(expf(dw), aw);
    float y1 = __fsub_rn(cy, __fmul_rn(0.5f, hh));
    float x1 = __fsub_rn(cx, __fmul_rn(0.5f, ww));
    float y2 = __fadd_rn(cy, __fmul_rn(0.5f, hh));
    float x2 = __fadd_rn(cx, __fmul_rn(0.5f, ww));
    y1 = fminf(fmaxf(y1, 0.0f), fh);
    y2 = fminf(fmaxf(y2, 0.0f), fh);
    x1 = fminf(fmaxf(x1, 0.0f), fw);
    x2 = fminf(fmaxf(x2, 0.0f), fw);
    float hs = __fsub_rn(y2, y1), wsz = __fsub_rn(x2, x1);
    bool ok = (hs >= 16.0f) && (wsz >= 16.0f);
    float l0 = sc18[2 * a], l1 = sc18[2 * a + 1];
    float m = fmaxf(l0, l1);
    float e0 = expf(__fsub_rn(l0, m));
    float e1 = expf(__fsub_rn(l1, m));
    float fg = __fdiv_rn(e1, __fadd_rn(e0, e1));
    float sc = ok ? fg : -1000000000.0f;
    int idx = hw * 9 + a;
    boxes_all[(size_t)n * NANCH + idx] = make_float4(y1, x1, y2, x2);
    k64[(size_t)n * NANCH + idx] = ((u64)(~fkey(sc)) << 16) | (u32)idx;  // asc key = desc score, tie: asc idx
  }
}

// ---------- exact top-2000 (stable) + bitonic sort ----------
__global__ __launch_bounds__(1024) void k_topk(const u64* __restrict__ k64_all,
                                               const float4* __restrict__ boxes_all,
                                               float4* __restrict__ boxes_sorted,
                                               float* __restrict__ sc_sorted) {
  const int b = blockIdx.x;
  const int tid = threadIdx.x;
  const u64* kb = k64_all + (size_t)b * NANCH;
  __shared__ u32 hist[4096];
  __shared__ u32 coarse[1024];
  __shared__ u64 sortbuf[2048];
  __shared__ u32 sh_bucket, sh_before, sh_cnt;
  u64 prefix = 0ull;
  u32 rank = NPRE;
  for (int pass = 0; pass < 4; ++pass) {
    const int shift = 36 - 12 * pass;
    for (int i = tid; i < 4096; i += 1024) hist[i] = 0;
    __syncthreads();
    for (int i = tid; i < NANCH; i += 1024) {
      u64 k = kb[i];
      if ((k >> (shift + 12)) == prefix)
        atomicAdd(&hist[(u32)((k >> shift) & 4095ull)], 1u);
    }
    __syncthreads();
    u32 s = hist[4 * tid] + hist[4 * tid + 1] + hist[4 * tid + 2] + hist[4 * tid + 3];
    coarse[tid] = s;
    __syncthreads();
    for (int off = 1; off < 1024; off <<= 1) {
      u32 v = (tid >= off) ? coarse[tid - off] : 0u;
      __syncthreads();
      coarse[tid] += v;
      __syncthreads();
    }
    u32 lo = (tid == 0) ? 0u : coarse[tid - 1];
    u32 hi = coarse[tid];
    if (lo < rank && rank <= hi) {
      u32 c = lo;
      #pragma unroll
      for (int q = 0; q < 4; ++q) {
        u32 nb = c + hist[4 * tid + q];
        if (c < rank && rank <= nb) { sh_bucket = 4 * tid + q; sh_before = c; break; }
        c = nb;
      }
    }
    __syncthreads();
    prefix = (prefix << 12) | (u64)sh_bucket;
    rank -= sh_before;
    __syncthreads();
  }
  const u64 Kstar = prefix;                 // exact rank-2000 key (keys distinct by idx)
  if (tid == 0) sh_cnt = 0;
  __syncthreads();
  for (int i = tid; i < NANCH; i += 1024) {
    u64 k = kb[i];
    if (k <= Kstar) {
      u32 p = atomicAdd(&sh_cnt, 1u);
      if (p < 2048) sortbuf[p] = k;
    }
  }
  __syncthreads();
  u32 cnt = sh_cnt;
  for (int i = tid; i < 2048; i += 1024)
    if (i >= (int)cnt) sortbuf[i] = ~0ull;
  __syncthreads();
  for (int kk = 2; kk <= 2048; kk <<= 1) {
    for (int j = kk >> 1; j > 0; j >>= 1) {
      int i1 = 2 * j * (tid / j) + (tid % j);
      int i2 = i1 + j;
      bool up = ((i1 & kk) == 0);
      u64 va = sortbuf[i1], vb = sortbuf[i2];
      if ((va > vb) == up) { sortbuf[i1] = vb; sortbuf[i2] = va; }
      __syncthreads();
    }
  }
  for (int i = tid; i < NPRE; i += 1024) {
    u64 k = sortbuf[i];
    u32 idx = (u32)(k & 0xFFFFull);
    boxes_sorted[(size_t)b * NPRE + i] = boxes_all[(size_t)b * NANCH + idx];
    sc_sorted[(size_t)b * NPRE + i] = unkey(~(u32)(k >> 16));
  }
}

// ---------- pairwise suppression bitmask ----------
__global__ __launch_bounds__(64) void k_supmask(const float4* __restrict__ boxes_sorted,
                                                u64* __restrict__ sup) {
  const int b = blockIdx.z;
  const int i = blockIdx.x * 64 + threadIdx.x;
  const int j0 = blockIdx.y * 64;
  __shared__ float4 bj[64];
  int jg = j0 + threadIdx.x;
  bj[threadIdx.x] = (jg < NPRE) ? boxes_sorted[(size_t)b * NPRE + jg] : make_float4(0, 0, 0, 0);
  __syncthreads();
  if (i >= NPRE) return;
  float4 bi = boxes_sorted[(size_t)b * NPRE + i];
  float ai = __fmul_rn(__fsub_rn(bi.z, bi.x), __fsub_rn(bi.w, bi.y));
  u64 m = 0;
  for (int q = 0; q < 64; ++q) {
    int j = j0 + q;
    float4 bb = bj[q];
    float ty = fmaxf(bi.x, bb.x);
    float tx = fmaxf(bi.y, bb.y);
    float by = fminf(bi.z, bb.z);
    float bx = fminf(bi.w, bb.w);
    float ih2 = fmaxf(__fsub_rn(by, ty), 0.0f);
    float iw2 = fmaxf(__fsub_rn(bx, tx), 0.0f);
    float inter = __fmul_rn(ih2, iw2);
    float aj = __fmul_rn(__fsub_rn(bb.z, bb.x), __fsub_rn(bb.w, bb.y));
    float den = __fadd_rn(__fsub_rn(__fadd_rn(ai, aj), inter), 1e-9f);
    float iou = __fdiv_rn(inter, den);
    if (iou > 0.7f && j > i && j < NPRE) m |= (1ull << q);
  }
  sup[((size_t)b * NPRE + i) * SUPW + blockIdx.y] = m;
}

// ---------- serial greedy NMS scan (1 wave per image) + rois write ----------
__global__ __launch_bounds__(64) void k_nms(const u64* __restrict__ sup,
                                            const float* __restrict__ sc_sorted,
                                            const float4* __restrict__ boxes_sorted,
                                            float* __restrict__ rois) {
  const int b = blockIdx.x;
  const int lane = threadIdx.x;
  __shared__ float sc[NPRE];
  for (int i = lane; i < NPRE; i += 64) sc[i] = sc_sorted[(size_t)b * NPRE + i];
  __syncthreads();
  const u64* supb = sup + (size_t)b * NPRE * SUPW;
  const float* bs = (const float*)(boxes_sorted + (size_t)b * NPRE);
  float* rb = rois + (size_t)b * NPOST * 4;
  u64 removed = 0ull;                       // lanes 0..31 each own one 64-bit word
  int kc = 0;
  for (int i = 0; i < NPRE; ++i) {
    int w = i >> 6;
    u64 rw = shfl_u64(removed, w);
    bool kept = (((rw >> (i & 63)) & 1ull) == 0ull) && (sc[i] > -5.0e8f);
    if (kept) {
      if (lane < 4) rb[(size_t)kc * 4 + lane] = bs[(size_t)i * 4 + lane];
      ++kc;
      if (kc >= NPOST) break;
      if (lane < 32) removed |= supb[(size_t)i * SUPW + lane];
    }
  }
  for (int z = lane; z < (NPOST - kc) * 4; z += 64) rb[(size_t)kc * 4 + z] = 0.0f;
}

// ---------- launch ----------
extern "C" void kernel_launch(void* const* d_in, const int* in_sizes, int n_in,
                              void* d_out, int out_size, void* d_ws, size_t ws_size,
                              hipStream_t stream) {
  const float* x  = (const float*)d_in[0];
  const float* w1 = (const float*)d_in[1];
  const float* b1 = (const float*)d_in[2];
  const float* sw = (const float*)d_in[3];
  const float* sb = (const float*)d_in[4];
  const float* lw = (const float*)d_in[5];
  const float* lb = (const float*)d_in[6];
  const int* ih   = (const int*)d_in[7];
  const int* iw   = (const int*)d_in[8];
  float* out = (float*)d_out;
  char* ws = (char*)d_ws;

  // workspace layout (regions aliased by liveness):
  float* hidden       = (float*)(ws + 0);            // 67,108,864 B  [conv..heads]
  float* wt           = (float*)(ws + 67108864ull);  //  9,437,184 B  [conv only]
  float* wt54         = (float*)(ws + 76546048ull);  //    114,688 B  [heads]
  float4* boxes_all   = (float4*)(ws + 67108864ull); //  4,718,592 B  [heads..topk] (aliases wt)
  u64*   k64          = (u64*)  (ws + 71827456ull);  //  2,359,296 B  [heads..topk]
  float4* boxes_sorted= (float4*)(ws + 0);           //    256,000 B  [topk..nms]   (aliases hidden)
  float* sc_sorted    = (float*)(ws + 262144ull);    //     64,000 B
  u64*   sup          = (u64*)  (ws + 327680ull);    //  4,096,000 B
  (void)in_sizes; (void)n_in; (void)out_size; (void)ws_size;

  k_transpose_w<<<9216, 256, 0, stream>>>(w1, wt);
  k_prep_small<<<144, 256, 0, stream>>>(sw, lw, wt54, out);
  k_conv3x3<<<dim3(32, 8, 8), 256, 0, stream>>>(x, wt, b1, hidden);
  k_heads<<<dim3(16, 8), 256, 0, stream>>>(hidden, wt54, sb, lb, ih, iw, out, boxes_all, k64);
  k_topk<<<8, 1024, 0, stream>>>(k64, boxes_all, boxes_sorted, sc_sorted);
  k_supmask<<<dim3(32, 32, 8), 64, 0, stream>>>(boxes_sorted, sup);
  k_nms<<<8, 64, 0, stream>>>(sup, sc_sorted, boxes_sorted, out + OUT_ROIS);
}